// Round 5
// baseline (105.274 us; speedup 1.0000x reference)
//
#include <hip/hip_runtime.h>
#include <hip/hip_bf16.h>

// B=64, IN=OUT=1024, E=8, H=8.
// y[b,o] = sum_e c[b,e] * (x[b,:] . weight[e,o,:])
// Kernel 0 (coef): c[b,e] chain (h0=0 so W_hh drops out) + zeroes y (poisoned).
// Kernel 1 (zgemm): grid (ot=32 o-tiles x kc=16 k-splits) = 512 blocks, 2/CU.
//   Stage x 64x64 once; stream 16 w-chunks (8e x 2 k-halves) with depth-2
//   register prefetch + double-buffered LDS; MFMA (A=w rows -> o, B=x rows -> b);
//   scale by c[b,e]; epilogue: unsafeAtomicAdd (HW global_atomic_add_f32,
//   fire-and-forget) directly into y — no z round-trip, no combine dispatch,
//   no fences (round 3: per-block __threadfence cost ~60 us of L2 wb/inv).

typedef short bf16x8 __attribute__((ext_vector_type(8)));
typedef float f32x4 __attribute__((ext_vector_type(4)));

__device__ __forceinline__ unsigned short f2bf(float f) {
    unsigned int u = __builtin_bit_cast(unsigned int, f);
    u += 0x7fffu + ((u >> 16) & 1u);
    return (unsigned short)(u >> 16);
}

#define XLDR 72  // x LDS row stride (shorts): 64 data + 8 pad
#define WLDR 40  // w LDS row stride (shorts): 32 data + 8 pad

__global__ __launch_bounds__(64) void coef_kernel(
    const float* __restrict__ x,          // [64,1024]
    const float* __restrict__ align_conv, // [8,8]
    const float* __restrict__ W_ih,       // [8,1]
    const float* __restrict__ b_ih,       // [8]
    const float* __restrict__ b_hh,       // [8]
    const float* __restrict__ W_att,      // [8,8]
    const float* __restrict__ b_att,      // [8]
    float* __restrict__ ct,               // [8,64] (e-major)
    float* __restrict__ y) {              // [64,1024] -> zero (harness poisons)
    const int b = blockIdx.x;
    const int lane = threadIdx.x;

    // zero this block's row of y (256 float4s / 64 lanes = 4 each, coalesced)
    float4* y4 = (float4*)y;
    const float4 zf4 = {0.f, 0.f, 0.f, 0.f};
#pragma unroll
    for (int i = 0; i < 4; ++i) y4[b * 256 + i * 64 + lane] = zf4;

    const float4* x4 = (const float4*)x;
    float s = 0.f;
#pragma unroll
    for (int i = 0; i < 4; ++i) {
        float4 v = x4[b * 256 + lane + i * 64];
        s += v.x + v.y + v.z + v.w;
    }
#pragma unroll
    for (int off = 32; off > 0; off >>= 1) s += __shfl_down(s, off, 64);
    if (lane == 0) {
        float pooled = s * (1.0f / 1024.0f);
        float rl[8];
#pragma unroll
        for (int j = 0; j < 8; ++j) {
            float h = tanhf(pooled * W_ih[j] + b_ih[j] + b_hh[j]);
            rl[j] = h > 0.f ? h : 0.f;
        }
        float lg[8];
        float mx = -1e30f;
#pragma unroll
        for (int f = 0; f < 8; ++f) {
            float a = b_att[f];
#pragma unroll
            for (int j = 0; j < 8; ++j) a += rl[j] * W_att[f * 8 + j];
            lg[f] = a;
            mx = fmaxf(mx, a);
        }
        float den = 0.f;
#pragma unroll
        for (int f = 0; f < 8; ++f) { lg[f] = __expf(lg[f] - mx); den += lg[f]; }
        float inv = 1.0f / den;
#pragma unroll
        for (int e = 0; e < 8; ++e) {
            float c = 0.f;
#pragma unroll
            for (int f = 0; f < 8; ++f) c += lg[f] * inv * align_conv[f * 8 + e];
            ct[e * 64 + b] = c;
        }
    }
}

__global__ __launch_bounds__(256, 2) void zgemm_kernel(
    const float* __restrict__ x,    // [64,1024]
    const float* __restrict__ w,    // [8,1024,1024]
    const float* __restrict__ ct,   // [8,64]
    float* __restrict__ y) {        // [64,1024] pre-zeroed; atomic accumulate
    __shared__ __align__(16) unsigned short xs[64 * XLDR];
    __shared__ __align__(16) unsigned short wl[2][32 * WLDR];
    __shared__ float csh[512];

    const int bid = blockIdx.x;     // grid = 512: ot fast, kc slow
    const int ot = bid & 31;
    const int kc = bid >> 5;        // 0..15
    const int o0 = ot * 32;

    const int t = threadIdx.x;
    const int lane = t & 63;
    const int wid = t >> 6;         // wave -> 16-wide b strip
    const int quad = lane >> 4;
    const int lr = lane & 15;

    const float4* x4 = (const float4*)x;
    const float4* w4 = (const float4*)w;

    // ---- stage x tile 64 rows x 64 cols (fp32 -> bf16) ----
#pragma unroll
    for (int p = 0; p < 4; ++p) {
        int row = (t >> 4) + p * 16, c4 = t & 15;
        float4 v = x4[row * 256 + kc * 16 + c4];
        ushort4 px;
        px.x = f2bf(v.x); px.y = f2bf(v.y); px.z = f2bf(v.z); px.w = f2bf(v.w);
        *(ushort4*)&xs[row * XLDR + c4 * 4] = px;
    }
    ((float2*)csh)[t] = ((const float2*)ct)[t];

    // ---- depth-2 register prefetch of w chunks (32 o-rows x 32 k each) ----
    const int wrow = t >> 3, wc4 = t & 7;
    const size_t wbase = (size_t)(o0 + wrow) * 256 + kc * 16 + wc4;
    float4 wr[2];
    wr[0] = w4[wbase];            // chunk 0: e=0, kh=0
    wr[1] = w4[wbase + 8];        // chunk 1: e=0, kh=1
    __syncthreads();

    // B-fragments from x (loop-invariant): two k-halves of the 64-span
    const int b = wid * 16 + lr;
    bf16x8 bf0 = *(const bf16x8*)&xs[b * XLDR + quad * 8];
    bf16x8 bf1 = *(const bf16x8*)&xs[b * XLDR + 32 + quad * 8];

    f32x4 accy[2], d[2];
    accy[0] = (f32x4){0.f, 0.f, 0.f, 0.f};
    accy[1] = (f32x4){0.f, 0.f, 0.f, 0.f};
    const f32x4 zero = (f32x4){0.f, 0.f, 0.f, 0.f};

    // ---- 16 chunks: ci = e*2 + kh ----
    for (int ci = 0; ci < 16; ++ci) {
        ushort4 pw;
        pw.x = f2bf(wr[ci & 1].x); pw.y = f2bf(wr[ci & 1].y);
        pw.z = f2bf(wr[ci & 1].z); pw.w = f2bf(wr[ci & 1].w);
        *(ushort4*)&wl[ci & 1][wrow * WLDR + wc4 * 4] = pw;
        __syncthreads();
        if (ci < 14) {
            int cn = ci + 2;      // prefetch two chunks ahead
            wr[ci & 1] = w4[wbase + (size_t)(cn >> 1) * 262144 + (cn & 1) * 8];
        }
        bf16x8 bcur = (ci & 1) ? bf1 : bf0;
        if ((ci & 1) == 0) {
#pragma unroll
            for (int mt = 0; mt < 2; ++mt) {
                bf16x8 a = *(const bf16x8*)&wl[ci & 1][(mt * 16 + lr) * WLDR + quad * 8];
                d[mt] = __builtin_amdgcn_mfma_f32_16x16x32_bf16(a, bcur, zero, 0, 0, 0);
            }
        } else {
            float cv = csh[(ci >> 1) * 64 + b];
#pragma unroll
            for (int mt = 0; mt < 2; ++mt) {
                bf16x8 a = *(const bf16x8*)&wl[ci & 1][(mt * 16 + lr) * WLDR + quad * 8];
                d[mt] = __builtin_amdgcn_mfma_f32_16x16x32_bf16(a, bcur, d[mt], 0, 0, 0);
                accy[mt][0] += cv * d[mt][0];
                accy[mt][1] += cv * d[mt][1];
                accy[mt][2] += cv * d[mt][2];
                accy[mt][3] += cv * d[mt][3];
            }
        }
    }

    // ---- epilogue: HW fp32 atomic add into y (fire-and-forget, no return) ----
    // D layout: col=lane&15 (=b), row=quad*4+reg (=o within 16-tile)
#pragma unroll
    for (int mt = 0; mt < 2; ++mt) {
        float* yp = &y[(b << 10) + o0 + mt * 16 + quad * 4];
#pragma unroll
        for (int rr = 0; rr < 4; ++rr)
            unsafeAtomicAdd(yp + rr, accy[mt][rr]);
    }
}

extern "C" void kernel_launch(void* const* d_in, const int* in_sizes, int n_in,
                              void* d_out, int out_size, void* d_ws, size_t ws_size,
                              hipStream_t stream) {
    const float* x          = (const float*)d_in[0];
    const float* weight     = (const float*)d_in[1];
    const float* align_conv = (const float*)d_in[2];
    const float* W_ih       = (const float*)d_in[3];
    // d_in[4] = W_hh unused (h0 == 0)
    const float* b_ih       = (const float*)d_in[5];
    const float* b_hh       = (const float*)d_in[6];
    const float* W_att      = (const float*)d_in[7];
    const float* b_att      = (const float*)d_in[8];
    float* y = (float*)d_out;

    float* ct = (float*)d_ws;                        // 512 floats

    coef_kernel<<<dim3(64), dim3(64), 0, stream>>>(x, align_conv, W_ih, b_ih,
                                                   b_hh, W_att, b_att, ct, y);
    zgemm_kernel<<<dim3(512), dim3(256), 0, stream>>>(x, weight, ct, y);
}

// Round 6
// 95.770 us; speedup vs baseline: 1.0992x; 1.0992x over previous
//
#include <hip/hip_runtime.h>
#include <hip/hip_bf16.h>

// B=64, IN=OUT=1024, E=8, H=8.
// y[b,o] = sum_e c[b,e] * (x[b,:] . weight[e,o,:])
// Kernel 0 (coef): c[b,e] chain (h0=0 so W_hh drops out).
// Kernel 1 (zgemm): grid (ot=32 o-tiles x kc=16 k-splits) = 512 blocks.
//   Per block: stage x 64x64 once; stream 16 w-chunks (8e x 2 k-halves) with
//   depth-2 register prefetch + double-buffered LDS; MFMA (A=w rows -> o,
//   B=x rows -> b); scale by c[b,e]; write e-free partial z[kc][b][o].
// Kernel 2 (combine): y[b,o] = sum_kc z — 4 MB coalesced read.
//
// Measured dead ends (do NOT reintroduce):
//  - Round 3: split-k via per-block __threadfence + atomic counter -> gfx950
//    emits buffer_wbl2/inv per block; zgemm went 5 -> 75 us (L2 wb/inv storm).
//  - Round 5: unsafeAtomicAdd epilogue into y -> 1M device-scope atomics with
//    16-way cross-XCD aliasing per address; total +7 us vs this structure.

typedef short bf16x8 __attribute__((ext_vector_type(8)));
typedef float f32x4 __attribute__((ext_vector_type(4)));

__device__ __forceinline__ unsigned short f2bf(float f) {
    unsigned int u = __builtin_bit_cast(unsigned int, f);
    u += 0x7fffu + ((u >> 16) & 1u);
    return (unsigned short)(u >> 16);
}

#define XLDR 72  // x LDS row stride (shorts): 64 data + 8 pad
#define WLDR 40  // w LDS row stride (shorts): 32 data + 8 pad

__global__ __launch_bounds__(64) void coef_kernel(
    const float* __restrict__ x,          // [64,1024]
    const float* __restrict__ align_conv, // [8,8]
    const float* __restrict__ W_ih,       // [8,1]
    const float* __restrict__ b_ih,       // [8]
    const float* __restrict__ b_hh,       // [8]
    const float* __restrict__ W_att,      // [8,8]
    const float* __restrict__ b_att,      // [8]
    float* __restrict__ ct) {             // [8,64] (e-major)
    const int b = blockIdx.x;
    const int lane = threadIdx.x;
    const float4* x4 = (const float4*)x;
    float s = 0.f;
#pragma unroll
    for (int i = 0; i < 4; ++i) {
        float4 v = x4[b * 256 + lane + i * 64];
        s += v.x + v.y + v.z + v.w;
    }
#pragma unroll
    for (int off = 32; off > 0; off >>= 1) s += __shfl_down(s, off, 64);
    if (lane == 0) {
        float pooled = s * (1.0f / 1024.0f);
        float rl[8];
#pragma unroll
        for (int j = 0; j < 8; ++j) {
            float h = tanhf(pooled * W_ih[j] + b_ih[j] + b_hh[j]);
            rl[j] = h > 0.f ? h : 0.f;
        }
        float lg[8];
        float mx = -1e30f;
#pragma unroll
        for (int f = 0; f < 8; ++f) {
            float a = b_att[f];
#pragma unroll
            for (int j = 0; j < 8; ++j) a += rl[j] * W_att[f * 8 + j];
            lg[f] = a;
            mx = fmaxf(mx, a);
        }
        float den = 0.f;
#pragma unroll
        for (int f = 0; f < 8; ++f) { lg[f] = __expf(lg[f] - mx); den += lg[f]; }
        float inv = 1.0f / den;
#pragma unroll
        for (int e = 0; e < 8; ++e) {
            float c = 0.f;
#pragma unroll
            for (int f = 0; f < 8; ++f) c += lg[f] * inv * align_conv[f * 8 + e];
            ct[e * 64 + b] = c;
        }
    }
}

__global__ __launch_bounds__(256, 2) void zgemm_kernel(
    const float* __restrict__ x,    // [64,1024]
    const float* __restrict__ w,    // [8,1024,1024]
    const float* __restrict__ ct,   // [8,64]
    float* __restrict__ z) {        // [16,64,1024] partials
    __shared__ __align__(16) unsigned short xs[64 * XLDR];
    __shared__ __align__(16) unsigned short wl[2][32 * WLDR];
    __shared__ float csh[512];

    const int bid = blockIdx.x;     // grid = 512: ot fast, kc slow
    const int ot = bid & 31;
    const int kc = bid >> 5;        // 0..15
    const int o0 = ot * 32;

    const int t = threadIdx.x;
    const int lane = t & 63;
    const int wid = t >> 6;         // wave -> 16-wide b strip
    const int quad = lane >> 4;
    const int lr = lane & 15;

    const float4* x4 = (const float4*)x;
    const float4* w4 = (const float4*)w;

    // ---- stage x tile 64 rows x 64 cols (fp32 -> bf16) ----
#pragma unroll
    for (int p = 0; p < 4; ++p) {
        int row = (t >> 4) + p * 16, c4 = t & 15;
        float4 v = x4[row * 256 + kc * 16 + c4];
        ushort4 px;
        px.x = f2bf(v.x); px.y = f2bf(v.y); px.z = f2bf(v.z); px.w = f2bf(v.w);
        *(ushort4*)&xs[row * XLDR + c4 * 4] = px;
    }
    ((float2*)csh)[t] = ((const float2*)ct)[t];

    // ---- depth-2 register prefetch of w chunks (32 o-rows x 32 k each) ----
    const int wrow = t >> 3, wc4 = t & 7;
    const size_t wbase = (size_t)(o0 + wrow) * 256 + kc * 16 + wc4;
    float4 wr[2];
    wr[0] = w4[wbase];            // chunk 0: e=0, kh=0
    wr[1] = w4[wbase + 8];        // chunk 1: e=0, kh=1
    __syncthreads();

    // B-fragments from x (loop-invariant): two k-halves of the 64-span
    const int b = wid * 16 + lr;
    bf16x8 bf0 = *(const bf16x8*)&xs[b * XLDR + quad * 8];
    bf16x8 bf1 = *(const bf16x8*)&xs[b * XLDR + 32 + quad * 8];

    f32x4 accy[2], d[2];
    accy[0] = (f32x4){0.f, 0.f, 0.f, 0.f};
    accy[1] = (f32x4){0.f, 0.f, 0.f, 0.f};
    const f32x4 zero = (f32x4){0.f, 0.f, 0.f, 0.f};

    // ---- 16 chunks: ci = e*2 + kh ----
    for (int ci = 0; ci < 16; ++ci) {
        ushort4 pw;
        pw.x = f2bf(wr[ci & 1].x); pw.y = f2bf(wr[ci & 1].y);
        pw.z = f2bf(wr[ci & 1].z); pw.w = f2bf(wr[ci & 1].w);
        *(ushort4*)&wl[ci & 1][wrow * WLDR + wc4 * 4] = pw;
        __syncthreads();
        if (ci < 14) {
            int cn = ci + 2;      // prefetch two chunks ahead
            wr[ci & 1] = w4[wbase + (size_t)(cn >> 1) * 262144 + (cn & 1) * 8];
        }
        bf16x8 bcur = (ci & 1) ? bf1 : bf0;
        if ((ci & 1) == 0) {
#pragma unroll
            for (int mt = 0; mt < 2; ++mt) {
                bf16x8 a = *(const bf16x8*)&wl[ci & 1][(mt * 16 + lr) * WLDR + quad * 8];
                d[mt] = __builtin_amdgcn_mfma_f32_16x16x32_bf16(a, bcur, zero, 0, 0, 0);
            }
        } else {
            float cv = csh[(ci >> 1) * 64 + b];
#pragma unroll
            for (int mt = 0; mt < 2; ++mt) {
                bf16x8 a = *(const bf16x8*)&wl[ci & 1][(mt * 16 + lr) * WLDR + quad * 8];
                d[mt] = __builtin_amdgcn_mfma_f32_16x16x32_bf16(a, bcur, d[mt], 0, 0, 0);
                accy[mt][0] += cv * d[mt][0];
                accy[mt][1] += cv * d[mt][1];
                accy[mt][2] += cv * d[mt][2];
                accy[mt][3] += cv * d[mt][3];
            }
        }
    }

    // ---- write partial z; D layout: col=lane&15 (=b), row=quad*4+reg (=o) ----
#pragma unroll
    for (int mt = 0; mt < 2; ++mt) {
        float4 out;
        out.x = accy[mt][0]; out.y = accy[mt][1]; out.z = accy[mt][2]; out.w = accy[mt][3];
        *(float4*)&z[(((size_t)(kc * 64 + b)) << 10) + o0 + mt * 16 + quad * 4] = out;
    }
}

__global__ __launch_bounds__(256) void combine_kernel(
    const float* __restrict__ z,  // [16,64,1024]
    float* __restrict__ y) {      // [64,1024]
    const int bid = blockIdx.x;   // (b, o-quarter)
    const int b = bid >> 2;
    const int oq = bid & 3;
    const int o = oq * 256 + threadIdx.x;
    float acc = 0.f;
#pragma unroll
    for (int kc = 0; kc < 16; ++kc)
        acc += z[(((size_t)(kc * 64 + b)) << 10) + o];
    y[(b << 10) + o] = acc;
}

extern "C" void kernel_launch(void* const* d_in, const int* in_sizes, int n_in,
                              void* d_out, int out_size, void* d_ws, size_t ws_size,
                              hipStream_t stream) {
    const float* x          = (const float*)d_in[0];
    const float* weight     = (const float*)d_in[1];
    const float* align_conv = (const float*)d_in[2];
    const float* W_ih       = (const float*)d_in[3];
    // d_in[4] = W_hh unused (h0 == 0)
    const float* b_ih       = (const float*)d_in[5];
    const float* b_hh       = (const float*)d_in[6];
    const float* W_att      = (const float*)d_in[7];
    const float* b_att      = (const float*)d_in[8];
    float* y = (float*)d_out;

    float* ct = (float*)d_ws;                        // 512 floats
    float* z  = (float*)((char*)d_ws + 4096);        // 16*64*1024 floats (4 MB)

    coef_kernel<<<dim3(64), dim3(64), 0, stream>>>(x, align_conv, W_ih, b_ih,
                                                   b_hh, W_att, b_att, ct);
    zgemm_kernel<<<dim3(512), dim3(256), 0, stream>>>(x, weight, ct, z);
    combine_kernel<<<dim3(256), dim3(256), 0, stream>>>(z, y);
}